// Round 13
// baseline (30.327 us; speedup 1.0000x reference)
//
#include <hip/hip_runtime.h>

#define DD 128   // feature dim, fixed by the reference

typedef float v2f __attribute__((ext_vector_type(2)));
typedef float v4f __attribute__((ext_vector_type(4)));
typedef float v8f __attribute__((ext_vector_type(8)));

// Packed per-pair update: z = x*a + c; zz = z*z; p *= (1 - zz); s += zz.
#define UPD2(P, S, XX, AA, CC)                                   \
    {                                                            \
        v2f z  = __builtin_elementwise_fma((XX), (AA), (CC));    \
        v2f zz = z * z;                                          \
        P = __builtin_elementwise_fma(-zz, P, P);                \
        S += zz;                                                 \
    }

// One row's update for a quad-pair (8 d) against a0/c0, a1/c1.
#define UPD8(P, S, XV)                                           \
    {                                                            \
        UPD2(P, S, (XV).lo.lo, a0.lo, c0.lo);                    \
        UPD2(P, S, (XV).lo.hi, a0.hi, c0.hi);                    \
        UPD2(P, S, (XV).hi.lo, a1.lo, c1.lo);                    \
        UPD2(P, S, (XV).hi.hi, a1.hi, c1.hi);                    \
    }

// Split-d structure: 64n x 64b tile, 1024 threads (16 waves).
//   waves 0-7  (dh=0): d in [0,64)   for rows bb + w8*8 .. +7
//   waves 8-15 (dh=1): d in [64,128) for the SAME rows
// Per-element instruction counts (ds_read, x-load, pk-FMA) are IDENTICAL to
// R11 (18.07 us) -- only wave-parallelism doubles (2 -> 4 waves/SIMD), which
// is the one lever R12 showed must not be bought with extra instructions.
// Partial products combine multiplicatively (exact): p = pA * pB via a
// conflict-free [8][512] LDS buffer.
// LDS: a/c [64 rows][32 quads] v4f XOR-swizzled (64 KB) + comb 16 KB = 80 KB.
// ~100 live regs < 128 cap of (1024,4); no arrays, no manual prefetch.
__global__ __launch_bounds__(1024, 4)
void wavelet_prod_kernel(const float* __restrict__ x,
                         const float* __restrict__ bias,
                         const float* __restrict__ scale,
                         float* __restrict__ out,
                         int B, int N)
{
    __shared__ v4f a_s[64 * 32];
    __shared__ v4f c_s[64 * 32];
    __shared__ float comb[8][512];

    const int tid  = threadIdx.x;
    const int lane = tid & 63;
    const int wave = tid >> 6;        // 0..15
    const int w8   = wave & 7;
    const int dh   = wave >> 3;       // d-half selector

    const int n0 = blockIdx.x * 64;   // 64 n per block (one per lane)
    const int bb = blockIdx.y * 64;   // 64 b per block (8 per wave-pair/thread)

    // ---- one-time staging: 64 x 128 bias/scale tile -> a,c in LDS ----
    {
        const v4f* b4 = (const v4f*)(bias  + (size_t)n0 * DD);
        const v4f* s4 = (const v4f*)(scale + (size_t)n0 * DD);
        #pragma unroll
        for (int k = 0; k < 2; ++k) {
            int flat = tid + k * 1024;         // 0..2047 v4f slots
            int r = flat >> 5;                 // row within tile (0..63)
            int q = flat & 31;                 // d-quad (0..31)
            v4f sv = s4[flat];
            v4f bv = b4[flat];
            v4f av, cv;
            av.x = __builtin_amdgcn_rcpf(sv.x);
            av.y = __builtin_amdgcn_rcpf(sv.y);
            av.z = __builtin_amdgcn_rcpf(sv.z);
            av.w = __builtin_amdgcn_rcpf(sv.w);
            cv = -bv * av;
            int dst = r * 32 + (q ^ (r & 7));
            a_s[dst] = av;
            c_s[dst] = cv;
        }
    }
    __syncthreads();

    const int b0 = __builtin_amdgcn_readfirstlane(bb + w8 * 8);
    // row stride 16 v8f; this thread's d-half starts 8 v8f in
    const v8f* xr8 = (const v8f*)(x + (size_t)b0 * DD) + dh * 8;

    const v4f* arow = a_s + lane * 32;
    const v4f* crow = c_s + lane * 32;
    const int sw    = lane & 7;
    const int qbase = dh * 16;        // this half's quad range: qbase..qbase+15
                                      // (q^sw flips only bits 0-2 -> stays in range)

    // Two packed chains per row, merged at each 32-d fold (16 factors/chain).
    v2f p0 = {1.f, 1.f}, p1 = {1.f, 1.f}, p2 = {1.f, 1.f}, p3 = {1.f, 1.f};
    v2f p4 = {1.f, 1.f}, p5 = {1.f, 1.f}, p6 = {1.f, 1.f}, p7 = {1.f, 1.f};
    v2f s0 = {0.f, 0.f}, s1 = {0.f, 0.f}, s2 = {0.f, 0.f}, s3 = {0.f, 0.f};
    v2f s4v = {0.f, 0.f}, s5 = {0.f, 0.f}, s6 = {0.f, 0.f}, s7 = {0.f, 0.f};

    const float kexp = -0.7213475204444817f;  // -0.5 * log2(e)

    #pragma unroll
    for (int w = 0; w < 2; ++w) {             // 2 folds of 32 d in this half
        #pragma unroll
        for (int h = 0; h < 4; ++h) {         // 4 quad-pairs per fold window
            const int q0  = qbase + w * 8 + h * 2;
            const int sl0 = q0 ^ sw;
            const int sl1 = (q0 + 1) ^ sw;
            v4f a0 = arow[sl0], c0 = crow[sl0];
            v4f a1 = arow[sl1], c1 = crow[sl1];
            const int xi = w * 4 + h;         // v8f index within half-row
            // rows in two groups of 4: <=4 v8f of x in flight
            {
                v8f xA0 = xr8[0 * 16 + xi];
                v8f xA1 = xr8[1 * 16 + xi];
                v8f xA2 = xr8[2 * 16 + xi];
                v8f xA3 = xr8[3 * 16 + xi];
                UPD8(p0, s0, xA0);
                UPD8(p1, s1, xA1);
                UPD8(p2, s2, xA2);
                UPD8(p3, s3, xA3);
            }
            {
                v8f xB0 = xr8[4 * 16 + xi];
                v8f xB1 = xr8[5 * 16 + xi];
                v8f xB2 = xr8[6 * 16 + xi];
                v8f xB3 = xr8[7 * 16 + xi];
                UPD8(p4, s4v, xB0);
                UPD8(p5, s5, xB1);
                UPD8(p6, s6, xB2);
                UPD8(p7, s7, xB3);
            }
        }
        // fold Gaussian factor + merge packed chains every 32 d
        p0.x = p0.x * p0.y * __builtin_amdgcn_exp2f((s0.x + s0.y) * kexp);
        p0.y = 1.f; s0 = (v2f){0.f, 0.f};
        p1.x = p1.x * p1.y * __builtin_amdgcn_exp2f((s1.x + s1.y) * kexp);
        p1.y = 1.f; s1 = (v2f){0.f, 0.f};
        p2.x = p2.x * p2.y * __builtin_amdgcn_exp2f((s2.x + s2.y) * kexp);
        p2.y = 1.f; s2 = (v2f){0.f, 0.f};
        p3.x = p3.x * p3.y * __builtin_amdgcn_exp2f((s3.x + s3.y) * kexp);
        p3.y = 1.f; s3 = (v2f){0.f, 0.f};
        p4.x = p4.x * p4.y * __builtin_amdgcn_exp2f((s4v.x + s4v.y) * kexp);
        p4.y = 1.f; s4v = (v2f){0.f, 0.f};
        p5.x = p5.x * p5.y * __builtin_amdgcn_exp2f((s5.x + s5.y) * kexp);
        p5.y = 1.f; s5 = (v2f){0.f, 0.f};
        p6.x = p6.x * p6.y * __builtin_amdgcn_exp2f((s6.x + s6.y) * kexp);
        p6.y = 1.f; s6 = (v2f){0.f, 0.f};
        p7.x = p7.x * p7.y * __builtin_amdgcn_exp2f((s7.x + s7.y) * kexp);
        p7.y = 1.f; s7 = (v2f){0.f, 0.f};
    }

    // ---- combine the two d-halves: p = pA * pB (exact) ----
    if (dh == 1) {
        const int pid = tid - 512;            // partner's tid
        comb[0][pid] = p0.x;
        comb[1][pid] = p1.x;
        comb[2][pid] = p2.x;
        comb[3][pid] = p3.x;
        comb[4][pid] = p4.x;
        comb[5][pid] = p5.x;
        comb[6][pid] = p6.x;
        comb[7][pid] = p7.x;
    }
    __syncthreads();
    if (dh == 0) {
        float* o = out + (size_t)b0 * N + n0 + lane;
        o[0 * N] = p0.x * comb[0][tid];
        o[1 * N] = p1.x * comb[1][tid];
        o[2 * N] = p2.x * comb[2][tid];
        o[3 * N] = p3.x * comb[3][tid];
        o[4 * N] = p4.x * comb[4][tid];
        o[5 * N] = p5.x * comb[5][tid];
        o[6 * N] = p6.x * comb[6][tid];
        o[7 * N] = p7.x * comb[7][tid];
    }
}

extern "C" void kernel_launch(void* const* d_in, const int* in_sizes, int n_in,
                              void* d_out, int out_size, void* d_ws, size_t ws_size,
                              hipStream_t stream)
{
    const float* x     = (const float*)d_in[0];
    const float* bias  = (const float*)d_in[1];
    const float* scale = (const float*)d_in[2];
    float* out = (float*)d_out;

    const int B = in_sizes[0] / DD;   // 2048
    const int N = in_sizes[1] / DD;   // 512

    dim3 grid(N / 64, B / 64);        // (8, 32) = 256 blocks = 1 per CU
    wavelet_prod_kernel<<<grid, 1024, 0, stream>>>(x, bias, scale, out, B, N);
}